// Round 4
// baseline (5027.744 us; speedup 1.0000x reference)
//
#include <hip/hip_runtime.h>

#define ZB 202
#define ZBP 208            // imgT row stride (floats): [0,1,2]=zeros(bands -3..-1), 3+z=band z
#define YX 65536
#define NTOT ((size_t)ZB * YX)

#define TILE 16            // pixels per register tile (16 VGPRs)
#define NT (YX / TILE)     // 4096 tiles

__device__ __forceinline__ constexpr float kMU() { return 0.0009765625f; }  // 2^-10
#define MINV (-32768.0f)
#define MAXV (32767.0f)

// ---------------------------------------------------------------------------
// Phase A: transpose img[z][t] -> imgT[t*ZBP + 3 + z], with imgT[t*ZBP+{0,1,2}]=0
// (zero-padded bands -3..-1) and tail offsets 205..207 zeroed. (unchanged,
// verified round 3)
// ---------------------------------------------------------------------------
__global__ __launch_bounds__(256) void tr_kernel(const float* __restrict__ img,
                                                 float* __restrict__ imgT) {
    __shared__ float lds[64 * 65];
    const int t0 = blockIdx.x * 64;
    const int zi = blockIdx.y;           // 0..3
    const int zw0 = zi * 64 - 3;         // window band base (offset zi*64 <-> band zw0)
    const int tid = threadIdx.x;
    const int c = tid & 63;
    const int r0 = tid >> 6;

    for (int k = 0; k < 16; ++k) {
        int rr = r0 * 16 + k;            // z-window row
        int z = zw0 + rr;
        float v = 0.0f;
        if (z >= 0 && z < ZB) v = img[(size_t)z * YX + t0 + c];  // coalesced along t
        lds[rr * 65 + c] = v;
    }
    __syncthreads();

    const int l = tid & 63;
    const int off = zi * 64 + l;         // imgT row offset
    if (off < ZBP) {                     // zi==3: only l<16
        for (int k = 0; k < 16; ++k) {
            int tr = r0 * 16 + k;
            imgT[(size_t)(t0 + tr) * ZBP + off] = lds[l * 65 + tr];  // coalesced along z
        }
    }
}

// ---------------------------------------------------------------------------
// Phase B: sequential sign-LMS scan. One wave per block, 4 blocks.
//
// Round-3 post-mortem: FETCH dropped 2.45x but time was flat -> bytes were
// never the wall.  Invariant across rounds 1-3: ~145 cyc per global_load_lds
// INSTRUCTION (16/tile, ~2300 cyc/tile) regardless of 1KB-vs-256B width =
// single-wave LDS-DMA path sustains only ~6 outstanding requests (~900 cyc
// HBM latency / 145).  Fix: abandon gload_lds; ordinary global_load_dword
// into a REGISTER pipeline supports ~63 outstanding per wave.
//   - 4 register tile-buffers x 16 floats = 64 VGPRs (fits, unlike round 0's
//     128-VGPR float4 buffer that the compiler refused to keep resident).
//   - loads batch-issued 3 tiles (48 steps ~ 2000 cyc) ahead, pinned with
//     sched_barrier(0); the compiler's register-dep tracking inserts exact
//     vmcnt waits (no hand-counted asm waits to miscount).
//   - neighbors {n0,n1,n2} = lanes l-1..l-3 of the same step via 3 __shfl_up
//     (no LDS at all).  Feeder lanes 0-2 get self-values from shfl (junk w
//     evolution, never stored); their OWN loaded values (stored zeros for
//     block 0) feed lanes 3-5 exactly as in the verified round-3 kernel.
//
// Recurrence kept bit-exact vs the verified kernel:
//  - identical float values reach identical ops in identical order
//    (n0,n1,n2,s here are the same bits as round-3's v.z,v.y,v.x,v.w).
//  - d: same 3-mul + left-to-right 2-add order; sign(s-clip(d))==sign(s-d);
//    w' = fma(+-MU, n, w); stores UNCLIPPED d (finalize clamps).
// ---------------------------------------------------------------------------
__global__ __launch_bounds__(64, 1) void scan_kernel(const float* __restrict__ imgT,
                                                     const float* __restrict__ w0g,
                                                     float* __restrict__ dT) {
    const int lane = threadIdx.x;
    const int b = blockIdx.x;                 // 0..3
    const int band = 61 * b + lane - 3;       // this lane's band (feeders: <61b or junk)
    const int goff = 61 * b + lane;           // imgT row offset to load (0..246)
    const bool do_store = (lane >= 3) && (band < ZB);
    const int wband = band < 0 ? 0 : (band > ZB - 1 ? ZB - 1 : band);

    float w0 = w0g[wband * 3 + 0];
    float w1 = w0g[wband * 3 + 1];
    float w2 = w0g[wband * 3 + 2];

    const float* gsrc = imgT + goff;          // +t*ZBP per step; 64 lanes contiguous
    float* outp = dT + wband;                 // dT[t][z] layout, stride ZB (finalize's)

    float R0[TILE], R1[TILE], R2[TILE], R3[TILE];

    // batch-issue one tile of per-lane dword loads; sched_barrier pins the
    // issue point (loads must not sink toward their uses)
#define STAGE(Rk, tile_)                                                       \
    {                                                                          \
        const float* gp = gsrc + (size_t)(tile_) * (TILE * ZBP);               \
        _Pragma("unroll") for (int k = 0; k < TILE; ++k)                       \
            Rk[k] = gp[(size_t)k * ZBP];                                       \
        __builtin_amdgcn_sched_barrier(0);                                     \
    }

#define COMPUTE(Rk, tile_)                                                     \
    {                                                                          \
        float* op = outp + (size_t)(tile_) * (TILE * ZB);                      \
        _Pragma("unroll") for (int i = 0; i < TILE; ++i) {                     \
            const float s = Rk[i];                                             \
            const float n0 = __shfl_up(s, 1, 64); /* band z-1 */               \
            const float n1 = __shfl_up(s, 2, 64); /* band z-2 */               \
            const float n2 = __shfl_up(s, 3, 64); /* band z-3 */               \
            float d = __fadd_rn(                                               \
                __fadd_rn(__fmul_rn(w0, n0), __fmul_rn(w1, n1)),               \
                __fmul_rn(w2, n2));                                            \
            float sg = (s > d) ? kMU() : ((s < d) ? -kMU() : 0.0f);            \
            w0 = __builtin_fmaf(sg, n0, w0);                                   \
            w1 = __builtin_fmaf(sg, n1, w1);                                   \
            w2 = __builtin_fmaf(sg, n2, w2);                                   \
            if (do_store) op[(size_t)i * ZB] = d;                              \
        }                                                                      \
    }

    // prologue: 3 tiles in flight
    STAGE(R0, 0);
    STAGE(R1, 1);
    STAGE(R2, 2);

    // steady state: stage tile t+3 before computing tile t (3-tile lookahead,
    // ~48 loads + stores in flight, throttled only by the 63-op vmcnt cap)
    int t = 0;
    for (; t + 8 <= NT; t += 4) {
        STAGE(R3, t + 3);
        COMPUTE(R0, t);
        STAGE(R0, t + 4);
        COMPUTE(R1, t + 1);
        STAGE(R1, t + 5);
        COMPUTE(R2, t + 2);
        STAGE(R2, t + 6);
        COMPUTE(R3, t + 3);
    }
    // exit with t = NT-4: R0..R2 hold tiles NT-4..NT-2; stage last, drain
    STAGE(R3, NT - 1);
    COMPUTE(R0, NT - 4);
    COMPUTE(R1, NT - 3);
    COMPUTE(R2, NT - 2);
    COMPUTE(R3, NT - 1);

#undef STAGE
#undef COMPUTE
}

// ---------------------------------------------------------------------------
// Phase C: elementwise outputs from dT + image. (unchanged, verified)
// ---------------------------------------------------------------------------
__global__ __launch_bounds__(256) void finalize_kernel(const float* __restrict__ img,
                                                       const float* __restrict__ dT,
                                                       float* __restrict__ out) {
    __shared__ float lds[64 * ZB];  // 51.7 KB
    const int t0 = blockIdx.x * 64;
    const float* src = dT + (size_t)t0 * ZB;
    for (int i = threadIdx.x; i < 64 * ZB; i += 256) lds[i] = src[i];
    __syncthreads();

    for (int k = 0; k < 51; ++k) {
        int e = k * 256 + threadIdx.x;
        if (e < 64 * ZB) {
            int zz = e >> 6;
            int tl = e & 63;
            float dv = lds[tl * ZB + zz];            // stride 202 -> 2-way bank alias (free)
            float pred = fminf(fmaxf(dv, MINV), MAXV);
            size_t o = (size_t)zz * YX + t0 + tl;
            float s = img[o];
            float res = __fsub_rn(s, pred);
            int q = (int)rintf(res);                  // round-half-even == jnp.round
            int m = (q >= 0) ? (2 * q) : (-2 * q - 1);
            out[o] = pred;                            // predictions
            out[NTOT + o] = res;                      // residuals
            out[2 * NTOT + o] = res;                  // quantized_residuals
            out[3 * NTOT + o] = (float)m;             // mapped_indices
            out[5 * NTOT + o] = __fadd_rn(pred, res); // reconstructed
        }
    }
}

// ---------------------------------------------------------------------------
// Phase D: sample_representatives = image. (unchanged)
// ---------------------------------------------------------------------------
__global__ __launch_bounds__(256) void repr_kernel(const float4* __restrict__ img4,
                                                   float4* __restrict__ out4) {
    size_t n4 = NTOT / 4;
    for (size_t i = (size_t)blockIdx.x * blockDim.x + threadIdx.x; i < n4;
         i += (size_t)gridDim.x * blockDim.x)
        out4[i] = img4[i];
}

extern "C" void kernel_launch(void* const* d_in, const int* in_sizes, int n_in,
                              void* d_out, int out_size, void* d_ws, size_t ws_size,
                              hipStream_t stream) {
    const float* img = (const float*)d_in[0];
    const float* w0g = (const float*)d_in[1];
    float* out = (float*)d_out;

    // Scratch carved out of d_out (dead before the final writers touch it):
    //   imgT = out[0 .. YX*ZBP+64) floats (13.6M floats = 54.5 MB << 4N;
    //          block 3's tail lanes read up to +246 past the last row: the
    //          +64 slack keeps those junk reads in-bounds)
    //   dT   = out[4N .. 5N) floats (later overwritten by repr_kernel)
    float* imgT = out;
    float* dT = out + 4 * NTOT;

    tr_kernel<<<dim3(YX / 64, 4), 256, 0, stream>>>(img, imgT);
    scan_kernel<<<4, 64, 0, stream>>>(imgT, w0g, dT);
    finalize_kernel<<<YX / 64, 256, 0, stream>>>(img, dT, out);
    repr_kernel<<<4096, 256, 0, stream>>>((const float4*)img, (float4*)(out + 4 * NTOT));
}

// Round 5
// 4156.805 us; speedup vs baseline: 1.2095x; 1.2095x over previous
//
#include <hip/hip_runtime.h>

#define ZB 202
#define ZBP 208            // imgT row stride (floats): [0,1,2]=zeros(bands -3..-1), 3+z=band z
#define YX 65536
#define NTOT ((size_t)ZB * YX)

#define SS 128             // steps per superstep (LDS: 2 x 128 x 256B = 64 KB)
#define NSS (YX / SS)      // 512 supersteps
#define PAD 4              // front slack so lanes 0-2's (lane-3) reads stay in-bounds

__device__ __forceinline__ constexpr float kMU() { return 0.0009765625f; }  // 2^-10
#define MINV (-32768.0f)
#define MAXV (32767.0f)

// global->LDS direct DMA, dword: per-lane global addr, LDS dest = uniform base + lane*4
#define GL_LDS4(g, l)                                                     \
    __builtin_amdgcn_global_load_lds(                                     \
        (const __attribute__((address_space(1))) void*)(g),               \
        (__attribute__((address_space(3))) void*)(l), 4, 0, 0)

// ---------------------------------------------------------------------------
// Phase A: transpose img[z][t] -> imgT[t*ZBP + 3 + z], with imgT[t*ZBP+{0,1,2}]=0
// (zero-padded bands -3..-1) and tail offsets 205..207 zeroed. (unchanged,
// verified round 3)
// ---------------------------------------------------------------------------
__global__ __launch_bounds__(256) void tr_kernel(const float* __restrict__ img,
                                                 float* __restrict__ imgT) {
    __shared__ float lds[64 * 65];
    const int t0 = blockIdx.x * 64;
    const int zi = blockIdx.y;           // 0..3
    const int zw0 = zi * 64 - 3;         // window band base
    const int tid = threadIdx.x;
    const int c = tid & 63;
    const int r0 = tid >> 6;

    for (int k = 0; k < 16; ++k) {
        int rr = r0 * 16 + k;
        int z = zw0 + rr;
        float v = 0.0f;
        if (z >= 0 && z < ZB) v = img[(size_t)z * YX + t0 + c];  // coalesced along t
        lds[rr * 65 + c] = v;
    }
    __syncthreads();

    const int l = tid & 63;
    const int off = zi * 64 + l;
    if (off < ZBP) {
        for (int k = 0; k < 16; ++k) {
            int tr = r0 * 16 + k;
            imgT[(size_t)(t0 + tr) * ZBP + off] = lds[l * 65 + tr];  // coalesced along z
        }
    }
}

// ---------------------------------------------------------------------------
// Phase B: sequential sign-LMS scan — PRODUCER/CONSUMER block, 8 waves.
//
// Rounds 0-4 post-mortem: ONE wave cannot get memory-level parallelism here.
//   - register prefetch buffers get sunk by the compiler (VGPR 96 / 48, not
//     the declared 128/64) -> just-in-time loads, full latency per step;
//   - single-wave global_load_lds sustains only ~6 outstanding requests
//     (~145 cyc per DMA instruction, independent of 1KB-vs-256B width).
// Fix: waves 1..7 are producers, each DMA-staging rows of the next superstep
// into a double-buffered LDS ring (7 waves x ~6 outstanding = ~42 in flight,
// hidden under the consumer's ~3800 cyc of compute per 128-step superstep).
// Wave 0 is the consumer running the unchanged recurrence; one __syncthreads
// per superstep (production of buf p^1 overlaps consumption of buf p).
//
// Consumer data path bit-exact vs verified round 3:
//   - LDS row r = imgT offsets [61b .. 61b+63] at pixel ss*SS+r (same bits);
//   - lane l: {n2,n1,n0,s} = row positions {l-3..l} via 4x ds_read_b32
//     (consecutive dwords -> 2-way bank alias = free; round 3 measured 0
//     conflicts), batched one 16-step sub-tile ahead (ra/rb ping-pong);
//   - d: same 3-mul + left-to-right 2-add order; sign(s-clip(d))==sign(s-d)
//     since |s| < 32767; w' = fma(+-MU, n, w); stores UNCLIPPED d (finalize
//     clamps).  Lanes 0-2 are feeders (do_store=false, junk w harmless).
// ---------------------------------------------------------------------------
__global__ __launch_bounds__(512, 1) void scan_kernel(const float* __restrict__ imgT,
                                                      const float* __restrict__ w0g,
                                                      float* __restrict__ dT) {
    __shared__ float ldsf[PAD + 2 * SS * 64];  // 64.02 KB

    const int tid = threadIdx.x;
    const int lane = tid & 63;
    const int wv = tid >> 6;                  // 0 = consumer, 1..7 = producers
    const int b = blockIdx.x;                 // 0..3
    const int goff = 61 * b + lane;           // imgT row offset this lane loads
    const float* gsrc = imgT + goff;

    // consumer-only state (harmless on producers)
    const int band = 61 * b + lane - 3;
    const bool do_store = (lane >= 3) && (band < ZB);
    const int wband = band < 0 ? 0 : (band > ZB - 1 ? ZB - 1 : band);
    float w0 = w0g[wband * 3 + 0];
    float w1 = w0g[wband * 3 + 1];
    float w2 = w0g[wband * 3 + 2];
    float* outp = dT + wband;                 // dT[t][z] layout, stride ZB

    // producer: stage superstep st into buffer st&1 (rows strided by 7 waves)
    auto stage = [&](int st) {
        float* lp = ldsf + PAD + (st & 1) * (SS * 64);
        const float* gp = gsrc + (size_t)st * (SS * ZBP);
        for (int r = wv - 1; r < SS; r += 7)
            GL_LDS4(gp + (size_t)r * ZBP, lp + r * 64);
    };

    float4 ra[16], rb[16];

#define RT(dst, st_)                                                           \
    {                                                                          \
        const int lb = PAD + (ss & 1) * (SS * 64) + (st_) * (16 * 64) + lane;  \
        _Pragma("unroll") for (int k = 0; k < 16; ++k) {                       \
            dst[k].x = ldsf[lb + k * 64 - 3];                                  \
            dst[k].y = ldsf[lb + k * 64 - 2];                                  \
            dst[k].z = ldsf[lb + k * 64 - 1];                                  \
            dst[k].w = ldsf[lb + k * 64 - 0];                                  \
        }                                                                      \
        __builtin_amdgcn_sched_barrier(0);                                     \
    }

#define CP(buf, st_)                                                           \
    {                                                                          \
        float* op = outp + ((size_t)ss * SS + (st_) * 16) * ZB;                \
        _Pragma("unroll") for (int i = 0; i < 16; ++i) {                       \
            const float4 v = buf[i];                                           \
            float d = __fadd_rn(                                               \
                __fadd_rn(__fmul_rn(w0, v.z), __fmul_rn(w1, v.y)),             \
                __fmul_rn(w2, v.x));                                           \
            float sg = (v.w > d) ? kMU() : ((v.w < d) ? -kMU() : 0.0f);        \
            w0 = __builtin_fmaf(sg, v.z, w0);                                  \
            w1 = __builtin_fmaf(sg, v.y, w1);                                  \
            w2 = __builtin_fmaf(sg, v.x, w2);                                  \
            if (do_store) op[(size_t)i * ZB] = d;                              \
        }                                                                      \
    }

    if (wv != 0) stage(0);
    __syncthreads();

    for (int ss = 0; ss < NSS; ++ss) {
        if (wv != 0) {
            if (ss + 1 < NSS) stage(ss + 1);
        } else {
            // 8 sub-tiles of 16 steps; batched reads one sub-tile ahead
            RT(ra, 0);
            RT(rb, 1); CP(ra, 0);
            RT(ra, 2); CP(rb, 1);
            RT(rb, 3); CP(ra, 2);
            RT(ra, 4); CP(rb, 3);
            RT(rb, 5); CP(ra, 4);
            RT(ra, 6); CP(rb, 5);
            RT(rb, 7); CP(ra, 6);
            CP(rb, 7);
        }
        __syncthreads();  // producers drained (vmcnt 0) before consumer reuses buffer
    }

#undef RT
#undef CP
}

// ---------------------------------------------------------------------------
// Phase C: elementwise outputs from dT + image. (unchanged, verified)
// ---------------------------------------------------------------------------
__global__ __launch_bounds__(256) void finalize_kernel(const float* __restrict__ img,
                                                       const float* __restrict__ dT,
                                                       float* __restrict__ out) {
    __shared__ float lds[64 * ZB];  // 51.7 KB
    const int t0 = blockIdx.x * 64;
    const float* src = dT + (size_t)t0 * ZB;
    for (int i = threadIdx.x; i < 64 * ZB; i += 256) lds[i] = src[i];
    __syncthreads();

    for (int k = 0; k < 51; ++k) {
        int e = k * 256 + threadIdx.x;
        if (e < 64 * ZB) {
            int zz = e >> 6;
            int tl = e & 63;
            float dv = lds[tl * ZB + zz];            // stride 202 -> 2-way bank alias (free)
            float pred = fminf(fmaxf(dv, MINV), MAXV);
            size_t o = (size_t)zz * YX + t0 + tl;
            float s = img[o];
            float res = __fsub_rn(s, pred);
            int q = (int)rintf(res);                  // round-half-even == jnp.round
            int m = (q >= 0) ? (2 * q) : (-2 * q - 1);
            out[o] = pred;                            // predictions
            out[NTOT + o] = res;                      // residuals
            out[2 * NTOT + o] = res;                  // quantized_residuals
            out[3 * NTOT + o] = (float)m;             // mapped_indices
            out[5 * NTOT + o] = __fadd_rn(pred, res); // reconstructed
        }
    }
}

// ---------------------------------------------------------------------------
// Phase D: sample_representatives = image. (unchanged)
// ---------------------------------------------------------------------------
__global__ __launch_bounds__(256) void repr_kernel(const float4* __restrict__ img4,
                                                   float4* __restrict__ out4) {
    size_t n4 = NTOT / 4;
    for (size_t i = (size_t)blockIdx.x * blockDim.x + threadIdx.x; i < n4;
         i += (size_t)gridDim.x * blockDim.x)
        out4[i] = img4[i];
}

extern "C" void kernel_launch(void* const* d_in, const int* in_sizes, int n_in,
                              void* d_out, int out_size, void* d_ws, size_t ws_size,
                              hipStream_t stream) {
    const float* img = (const float*)d_in[0];
    const float* w0g = (const float*)d_in[1];
    float* out = (float*)d_out;

    // Scratch carved out of d_out (dead before the final writers touch it):
    //   imgT = out[0 .. YX*ZBP+64) floats (54.5 MB << 4N; +64 slack keeps
    //          block 3's tail-lane junk reads in-bounds)
    //   dT   = out[4N .. 5N) floats (later overwritten by repr_kernel)
    float* imgT = out;
    float* dT = out + 4 * NTOT;

    tr_kernel<<<dim3(YX / 64, 4), 256, 0, stream>>>(img, imgT);
    scan_kernel<<<4, 512, 0, stream>>>(imgT, w0g, dT);
    finalize_kernel<<<YX / 64, 256, 0, stream>>>(img, dT, out);
    repr_kernel<<<4096, 256, 0, stream>>>((const float4*)img, (float4*)(out + 4 * NTOT));
}

// Round 6
// 3920.055 us; speedup vs baseline: 1.2826x; 1.0604x over previous
//
#include <hip/hip_runtime.h>

#define ZB 202
#define ZBP 208            // imgT row stride (floats): [0,1,2]=zeros(bands -3..-1), 3+z=band z
#define YX 65536
#define NTOT ((size_t)ZB * YX)

#define SS 128             // steps per superstep (LDS: 2 x 128 x 256B = 64 KB)
#define NSS (YX / SS)      // 512 supersteps
#define PAD 4              // front slack so lanes 0-2's (lane-3) reads stay in-bounds

__device__ __forceinline__ constexpr float kMU() { return 0.0009765625f; }  // 2^-10
#define MINV (-32768.0f)
#define MAXV (32767.0f)

typedef float v2f __attribute__((ext_vector_type(2)));

// global->LDS direct DMA, dword: per-lane global addr, LDS dest = uniform base + lane*4
#define GL_LDS4(g, l)                                                     \
    __builtin_amdgcn_global_load_lds(                                     \
        (const __attribute__((address_space(1))) void*)(g),               \
        (__attribute__((address_space(3))) void*)(l), 4, 0, 0)

// ---------------------------------------------------------------------------
// Phase A: transpose img[z][t] -> imgT[t*ZBP + 3 + z], with imgT[t*ZBP+{0,1,2}]=0
// (zero-padded bands -3..-1) and tail offsets 205..207 zeroed. (unchanged,
// verified round 3)
// ---------------------------------------------------------------------------
__global__ __launch_bounds__(256) void tr_kernel(const float* __restrict__ img,
                                                 float* __restrict__ imgT) {
    __shared__ float lds[64 * 65];
    const int t0 = blockIdx.x * 64;
    const int zi = blockIdx.y;           // 0..3
    const int zw0 = zi * 64 - 3;         // window band base
    const int tid = threadIdx.x;
    const int c = tid & 63;
    const int r0 = tid >> 6;

    for (int k = 0; k < 16; ++k) {
        int rr = r0 * 16 + k;
        int z = zw0 + rr;
        float v = 0.0f;
        if (z >= 0 && z < ZB) v = img[(size_t)z * YX + t0 + c];  // coalesced along t
        lds[rr * 65 + c] = v;
    }
    __syncthreads();

    const int l = tid & 63;
    const int off = zi * 64 + l;
    if (off < ZBP) {
        for (int k = 0; k < 16; ++k) {
            int tr = r0 * 16 + k;
            imgT[(size_t)(t0 + tr) * ZBP + off] = lds[l * 65 + tr];  // coalesced along z
        }
    }
}

// ---------------------------------------------------------------------------
// Phase B: sequential sign-LMS scan — producer/consumer block, 8 waves.
//
// Round-5 post-mortem: producers are fine; the CONSUMER is the wall, and has
// been since round 1 (136-161 cyc/step = exposed ds_read latency).  VGPR=80
// proved the C++-coded read buffers were sunk to their uses AGAIN (4th time):
// sched_barrier pins the machine scheduler but not the IR passes that place
// loads.  Fix: issue the LDS reads as INLINE-ASM ds_read2_b32 (volatile asm
// defs must be register-allocated and cannot be sunk), 32 reads batched per
// 16-step sub-tile, one s_waitcnt lgkmcnt(0) + sched_barrier(0) before the
// consuming sub-tile (guide rule #18 pattern).  Sub-tiles double-buffered so
// each batch's retirement hides under the previous sub-tile's ~450cyc chain.
//
// Data path bit-exact vs verified rounds 3/5:
//   - dst[k].{x,y,z,w} = LDS dwords at row positions {lane-3..lane} — the
//     exact dword positions round 5 read; identical values flow through the
//     identical op sequence (3-mul + left-to-right 2-add; sign(s-clip(d)) ==
//     sign(s-d) since |s| < 32767; w' = fma(+-MU, n, w); stores UNCLIPPED d).
//   - lanes 0-2 are feeders (do_store=false, junk w harmless).
// ---------------------------------------------------------------------------
__global__ __launch_bounds__(512, 1) void scan_kernel(const float* __restrict__ imgT,
                                                      const float* __restrict__ w0g,
                                                      float* __restrict__ dT) {
    __shared__ float ldsf[PAD + 2 * SS * 64];  // 64.02 KB

    const int tid = threadIdx.x;
    const int lane = tid & 63;
    const int wv = tid >> 6;                  // 0 = consumer, 1..7 = producers
    const int b = blockIdx.x;                 // 0..3
    const int goff = 61 * b + lane;           // imgT row offset this lane loads
    const float* gsrc = imgT + goff;

    // consumer-only state (harmless on producers)
    const int band = 61 * b + lane - 3;
    const bool do_store = (lane >= 3) && (band < ZB);
    const int wband = band < 0 ? 0 : (band > ZB - 1 ? ZB - 1 : band);
    float w0 = w0g[wband * 3 + 0];
    float w1 = w0g[wband * 3 + 1];
    float w2 = w0g[wband * 3 + 2];
    float* outp = dT + wband;                 // dT[t][z] layout, stride ZB

    // producer: stage superstep st into buffer st&1 (rows strided by 7 waves)
    auto stage = [&](int st) {
        float* lp = ldsf + PAD + (st & 1) * (SS * 64);
        const float* gp = gsrc + (size_t)st * (SS * ZBP);
        for (int r = wv - 1; r < SS; r += 7)
            GL_LDS4(gp + (size_t)r * ZBP, lp + r * 64);
    };

    float4 ra[16], rb[16];

    // batch-ISSUE one 16-step sub-tile: 16x asm {ds_read2_b32 x2} -> 64 dwords.
    // Volatile asm defs are unsinkable; data is valid only after KWAIT().
#define RTISSUE(dst, st_)                                                      \
    {                                                                          \
        uint32_t a0 = (uint32_t)(size_t)(__attribute__((address_space(3)))     \
            float*)(ldsf + (PAD + (ss & 1) * (SS * 64) + (st_) * (16 * 64)     \
                            + lane - 3));                                      \
        _Pragma("unroll") for (int k = 0; k < 16; ++k) {                       \
            v2f p01, p23;                                                      \
            uint32_t a = a0 + (uint32_t)(k * 256);                             \
            asm volatile("ds_read2_b32 %0, %2 offset0:0 offset1:1\n\t"         \
                         "ds_read2_b32 %1, %2 offset0:2 offset1:3"             \
                         : "=v"(p01), "=v"(p23)                                \
                         : "v"(a));                                            \
            dst[k].x = p01.x; dst[k].y = p01.y;                                \
            dst[k].z = p23.x; dst[k].w = p23.y;                                \
        }                                                                      \
    }

    // drain the asm reads; sched_barrier keeps consumers from hoisting above
#define KWAIT()                                                                \
    {                                                                          \
        asm volatile("s_waitcnt lgkmcnt(0)" ::: "memory");                     \
        __builtin_amdgcn_sched_barrier(0);                                     \
    }

#define CP(buf, st_)                                                           \
    {                                                                          \
        float* op = outp + ((size_t)ss * SS + (st_) * 16) * ZB;                \
        _Pragma("unroll") for (int i = 0; i < 16; ++i) {                       \
            const float4 v = buf[i];                                           \
            float d = __fadd_rn(                                               \
                __fadd_rn(__fmul_rn(w0, v.z), __fmul_rn(w1, v.y)),             \
                __fmul_rn(w2, v.x));                                           \
            float sg = (v.w > d) ? kMU() : ((v.w < d) ? -kMU() : 0.0f);        \
            w0 = __builtin_fmaf(sg, v.z, w0);                                  \
            w1 = __builtin_fmaf(sg, v.y, w1);                                  \
            w2 = __builtin_fmaf(sg, v.x, w2);                                  \
            if (do_store) op[(size_t)i * ZB] = d;                              \
        }                                                                      \
    }

    if (wv != 0) stage(0);
    __syncthreads();

    for (int ss = 0; ss < NSS; ++ss) {
        if (wv != 0) {
            if (ss + 1 < NSS) stage(ss + 1);
        } else {
            // 8 sub-tiles of 16 steps; batch-issue one sub-tile ahead so the
            // reads retire under the previous sub-tile's compute chain
            RTISSUE(ra, 0); KWAIT();
            RTISSUE(rb, 1); CP(ra, 0); KWAIT();
            RTISSUE(ra, 2); CP(rb, 1); KWAIT();
            RTISSUE(rb, 3); CP(ra, 2); KWAIT();
            RTISSUE(ra, 4); CP(rb, 3); KWAIT();
            RTISSUE(rb, 5); CP(ra, 4); KWAIT();
            RTISSUE(ra, 6); CP(rb, 5); KWAIT();
            RTISSUE(rb, 7); CP(ra, 6); KWAIT();
            CP(rb, 7);
        }
        __syncthreads();  // producers drained before consumer reuses buffer
    }

#undef RTISSUE
#undef KWAIT
#undef CP
}

// ---------------------------------------------------------------------------
// Phase C: elementwise outputs from dT + image. (unchanged, verified)
// ---------------------------------------------------------------------------
__global__ __launch_bounds__(256) void finalize_kernel(const float* __restrict__ img,
                                                       const float* __restrict__ dT,
                                                       float* __restrict__ out) {
    __shared__ float lds[64 * ZB];  // 51.7 KB
    const int t0 = blockIdx.x * 64;
    const float* src = dT + (size_t)t0 * ZB;
    for (int i = threadIdx.x; i < 64 * ZB; i += 256) lds[i] = src[i];
    __syncthreads();

    for (int k = 0; k < 51; ++k) {
        int e = k * 256 + threadIdx.x;
        if (e < 64 * ZB) {
            int zz = e >> 6;
            int tl = e & 63;
            float dv = lds[tl * ZB + zz];            // stride 202 -> 2-way bank alias (free)
            float pred = fminf(fmaxf(dv, MINV), MAXV);
            size_t o = (size_t)zz * YX + t0 + tl;
            float s = img[o];
            float res = __fsub_rn(s, pred);
            int q = (int)rintf(res);                  // round-half-even == jnp.round
            int m = (q >= 0) ? (2 * q) : (-2 * q - 1);
            out[o] = pred;                            // predictions
            out[NTOT + o] = res;                      // residuals
            out[2 * NTOT + o] = res;                  // quantized_residuals
            out[3 * NTOT + o] = (float)m;             // mapped_indices
            out[5 * NTOT + o] = __fadd_rn(pred, res); // reconstructed
        }
    }
}

// ---------------------------------------------------------------------------
// Phase D: sample_representatives = image. (unchanged)
// ---------------------------------------------------------------------------
__global__ __launch_bounds__(256) void repr_kernel(const float4* __restrict__ img4,
                                                   float4* __restrict__ out4) {
    size_t n4 = NTOT / 4;
    for (size_t i = (size_t)blockIdx.x * blockDim.x + threadIdx.x; i < n4;
         i += (size_t)gridDim.x * blockDim.x)
        out4[i] = img4[i];
}

extern "C" void kernel_launch(void* const* d_in, const int* in_sizes, int n_in,
                              void* d_out, int out_size, void* d_ws, size_t ws_size,
                              hipStream_t stream) {
    const float* img = (const float*)d_in[0];
    const float* w0g = (const float*)d_in[1];
    float* out = (float*)d_out;

    // Scratch carved out of d_out (dead before the final writers touch it):
    //   imgT = out[0 .. YX*ZBP+64) floats (54.5 MB << 4N; +64 slack keeps
    //          block 3's tail-lane junk reads in-bounds)
    //   dT   = out[4N .. 5N) floats (later overwritten by repr_kernel)
    float* imgT = out;
    float* dT = out + 4 * NTOT;

    tr_kernel<<<dim3(YX / 64, 4), 256, 0, stream>>>(img, imgT);
    scan_kernel<<<4, 512, 0, stream>>>(imgT, w0g, dT);
    finalize_kernel<<<YX / 64, 256, 0, stream>>>(img, dT, out);
    repr_kernel<<<4096, 256, 0, stream>>>((const float4*)img, (float4*)(out + 4 * NTOT));
}